// Round 1
// baseline (514.044 us; speedup 1.0000x reference)
//
#include <hip/hip_runtime.h>

// Guided blur (multichannel guided filter), B=8, C=Cp=3, H=W=512, k=5, eps=1e-4.
// Pass 1: blur 21 channels (I, p, I*I, I*p) per 32x32 tile, per-pixel 3x3 solve -> a[9], b[3] in d_ws.
// Pass 2: blur a,b (12 ch) per tile, combine with guidance -> out.
// d_ws usage: 8*12*512*512*4 = 100,663,296 bytes.

namespace {

constexpr int BN = 8;        // batch
constexpr int HH = 512;
constexpr int WW = 512;
constexpr float GEPS = 1e-4f;
constexpr int TILE = 32;
constexpr int HALO = 2;      // k//2
constexpr int LW = TILE + 2 * HALO;   // 36
constexpr int LST = LW + 1;           // 37: +1 pad, conflict-free rows

__device__ __forceinline__ int refl(int i, int n) {
    // jnp.pad(..., mode='reflect'): -1 -> 1, -2 -> 2, n -> n-2, n+1 -> n-3
    if (i < 0) i = -i;
    if (i >= n) i = 2 * n - 2 - i;
    return i;
}

__global__ __launch_bounds__(128) void pass1_kernel(
        const float* __restrict__ g, const float* __restrict__ p,
        float* __restrict__ ab) {
    __shared__ float sb[6][LW][LST];
    const int x0 = blockIdx.x * TILE, y0 = blockIdx.y * TILE;
    const int bb = blockIdx.z;
    const int tx = threadIdx.x, ty = threadIdx.y;
    const int tid = ty * 32 + tx;
    const int csz = HH * WW;

    // Stage 6 base channel tiles (guidance 0..2, input 3..5) with reflect halo.
    for (int idx = tid; idx < 6 * LW * LW; idx += 128) {
        int c = idx / (LW * LW);
        int rem = idx - c * (LW * LW);
        int ly = rem / LW, lx = rem - ly * LW;
        int gy = refl(y0 + ly - HALO, HH);
        int gx = refl(x0 + lx - HALO, WW);
        const float* src = (c < 3) ? (g + (bb * 3 + c) * csz)
                                   : (p + (bb * 3 + (c - 3)) * csz);
        sb[c][ly][lx] = src[gy * WW + gx];
    }
    __syncthreads();

    const int col = tx;      // LDS col base; pixel col tx has window cols tx..tx+4
    const int r0 = ty * 8;   // this thread handles tile rows r0..r0+7 (window LDS rows r..r+4)

    float S[21];             // running 5x5 window sums
#pragma unroll
    for (int i = 0; i < 21; ++i) S[i] = 0.f;
    float h[21];             // one-row horizontal 5-sums

    auto rowh = [&](int row) {
#pragma unroll
        for (int i = 0; i < 21; ++i) h[i] = 0.f;
#pragma unroll
        for (int dx = 0; dx < 5; ++dx) {
            float i0 = sb[0][row][col + dx];
            float i1 = sb[1][row][col + dx];
            float i2 = sb[2][row][col + dx];
            float q0 = sb[3][row][col + dx];
            float q1 = sb[4][row][col + dx];
            float q2 = sb[5][row][col + dx];
            h[0] += i0;  h[1] += i1;  h[2] += i2;
            h[3] += q0;  h[4] += q1;  h[5] += q2;
            h[6]  += i0 * i0; h[7]  += i0 * i1; h[8]  += i0 * i2;
            h[9]  += i1 * i1; h[10] += i1 * i2; h[11] += i2 * i2;
            h[12] += i0 * q0; h[13] += i0 * q1; h[14] += i0 * q2;
            h[15] += i1 * q0; h[16] += i1 * q1; h[17] += i1 * q2;
            h[18] += i2 * q0; h[19] += i2 * q1; h[20] += i2 * q2;
        }
    };

    // Prime with window rows r0..r0+3.
    for (int rr = 0; rr < 4; ++rr) {
        rowh(r0 + rr);
#pragma unroll
        for (int i = 0; i < 21; ++i) S[i] += h[i];
    }

    const int x = x0 + tx;
    for (int j = 0; j < 8; ++j) {
        rowh(r0 + 4 + j);   // add bottom row of this pixel's window
#pragma unroll
        for (int i = 0; i < 21; ++i) S[i] += h[i];

        // ---- finalize pixel (y0+r0+j, x) ----
        const float nrm = 0.04f;  // 1/25
        float mI0 = S[0] * nrm, mI1 = S[1] * nrm, mI2 = S[2] * nrm;
        float mP0 = S[3] * nrm, mP1 = S[4] * nrm, mP2 = S[5] * nrm;
        float v00 = S[6]  * nrm - mI0 * mI0 + GEPS;
        float v01 = S[7]  * nrm - mI0 * mI1;
        float v02 = S[8]  * nrm - mI0 * mI2;
        float v11 = S[9]  * nrm - mI1 * mI1 + GEPS;
        float v12 = S[10] * nrm - mI1 * mI2;
        float v22 = S[11] * nrm - mI2 * mI2 + GEPS;
        float c00 = S[12] * nrm - mI0 * mP0;
        float c01 = S[13] * nrm - mI0 * mP1;
        float c02 = S[14] * nrm - mI0 * mP2;
        float c10 = S[15] * nrm - mI1 * mP0;
        float c11 = S[16] * nrm - mI1 * mP1;
        float c12 = S[17] * nrm - mI1 * mP2;
        float c20 = S[18] * nrm - mI2 * mP0;
        float c21 = S[19] * nrm - mI2 * mP1;
        float c22 = S[20] * nrm - mI2 * mP2;
        // symmetric 3x3 inverse via adjugate
        float i00 = v11 * v22 - v12 * v12;
        float i01 = v02 * v12 - v01 * v22;
        float i02 = v01 * v12 - v02 * v11;
        float i11 = v00 * v22 - v02 * v02;
        float i12 = v01 * v02 - v00 * v12;
        float i22 = v00 * v11 - v01 * v01;
        float det = v00 * i00 + v01 * i01 + v02 * i02;
        float rd  = 1.0f / det;  // det > 0: A = PSD + eps*I
        float a00 = (i00 * c00 + i01 * c10 + i02 * c20) * rd;
        float a01 = (i00 * c01 + i01 * c11 + i02 * c21) * rd;
        float a02 = (i00 * c02 + i01 * c12 + i02 * c22) * rd;
        float a10 = (i01 * c00 + i11 * c10 + i12 * c20) * rd;
        float a11 = (i01 * c01 + i11 * c11 + i12 * c21) * rd;
        float a12 = (i01 * c02 + i11 * c12 + i12 * c22) * rd;
        float a20 = (i02 * c00 + i12 * c10 + i22 * c20) * rd;
        float a21 = (i02 * c01 + i12 * c11 + i22 * c21) * rd;
        float a22 = (i02 * c02 + i12 * c12 + i22 * c22) * rd;
        // b_p = mean_p_p - sum_c a[c][p] * mean_I_c
        float b0 = mP0 - (a00 * mI0 + a10 * mI1 + a20 * mI2);
        float b1 = mP1 - (a01 * mI0 + a11 * mI1 + a21 * mI2);
        float b2 = mP2 - (a02 * mI0 + a12 * mI1 + a22 * mI2);

        int y = y0 + r0 + j;
        int base = (bb * 12) * csz + y * WW + x;
        ab[base + 0  * csz] = a00;
        ab[base + 1  * csz] = a01;
        ab[base + 2  * csz] = a02;
        ab[base + 3  * csz] = a10;
        ab[base + 4  * csz] = a11;
        ab[base + 5  * csz] = a12;
        ab[base + 6  * csz] = a20;
        ab[base + 7  * csz] = a21;
        ab[base + 8  * csz] = a22;
        ab[base + 9  * csz] = b0;
        ab[base + 10 * csz] = b1;
        ab[base + 11 * csz] = b2;

        if (j < 7) {
            rowh(r0 + j);   // remove top row of this pixel's window
#pragma unroll
            for (int i = 0; i < 21; ++i) S[i] -= h[i];
        }
    }
}

__global__ __launch_bounds__(128) void pass2_kernel(
        const float* __restrict__ g, const float* __restrict__ ab,
        float* __restrict__ out) {
    __shared__ float sa[LW][LST];
    const int x0 = blockIdx.x * TILE, y0 = blockIdx.y * TILE;
    const int bb = blockIdx.z;
    const int tx = threadIdx.x, ty = threadIdx.y;
    const int tid = ty * 32 + tx;
    const int r0 = ty * 8;
    const int x = x0 + tx;
    const int csz = HH * WW;

    // guidance for my 8 pixels x 3 channels
    float gv[3][8];
#pragma unroll
    for (int c = 0; c < 3; ++c)
#pragma unroll
        for (int j = 0; j < 8; ++j)
            gv[c][j] = g[(bb * 3 + c) * csz + (y0 + r0 + j) * WW + x];

    float acc[3][8];
#pragma unroll
    for (int pp = 0; pp < 3; ++pp)
#pragma unroll
        for (int j = 0; j < 8; ++j) acc[pp][j] = 0.f;

#pragma unroll
    for (int ch = 0; ch < 12; ++ch) {
        __syncthreads();   // protect previous channel's reads
        const float* src = ab + (bb * 12 + ch) * csz;
        for (int idx = tid; idx < LW * LW; idx += 128) {
            int ly = idx / LW, lx = idx - ly * LW;
            sa[ly][lx] = src[refl(y0 + ly - HALO, HH) * WW + refl(x0 + lx - HALO, WW)];
        }
        __syncthreads();

        // vertical rolling window over 12 row-hsums (ring buffer of 5)
        float ring[5];
        float wsum = 0.f;
#pragma unroll
        for (int rr = 0; rr < 12; ++rr) {
            float hs = 0.f;
#pragma unroll
            for (int dx = 0; dx < 5; ++dx) hs += sa[r0 + rr][tx + dx];
            if (rr >= 5) wsum -= ring[rr % 5];
            wsum += hs;
            ring[rr % 5] = hs;
            if (rr >= 4) {
                float mean = wsum * 0.04f;
                int j = rr - 4;
                if (ch < 9) acc[ch % 3][j] += mean * gv[ch / 3][j];
                else        acc[ch - 9][j] += mean;
            }
        }
    }

#pragma unroll
    for (int pp = 0; pp < 3; ++pp)
#pragma unroll
        for (int j = 0; j < 8; ++j)
            out[(bb * 3 + pp) * csz + (y0 + r0 + j) * WW + x] = acc[pp][j];
}

}  // namespace

extern "C" void kernel_launch(void* const* d_in, const int* in_sizes, int n_in,
                              void* d_out, int out_size, void* d_ws, size_t ws_size,
                              hipStream_t stream) {
    const float* g  = (const float*)d_in[0];   // guidance [8,3,512,512]
    const float* p  = (const float*)d_in[1];   // input    [8,3,512,512]
    float* out = (float*)d_out;                // [8,3,512,512]
    float* ab  = (float*)d_ws;                 // [8,12,512,512] a(9)+b(3); needs ~96 MB

    dim3 grid(WW / TILE, HH / TILE, BN);       // 16 x 16 x 8 = 2048 blocks
    dim3 block(32, 4);                         // 128 threads, 2 waves

    hipLaunchKernelGGL(pass1_kernel, grid, block, 0, stream, g, p, ab);
    hipLaunchKernelGGL(pass2_kernel, grid, block, 0, stream, g, ab, out);
}

// Round 2
// 253.195 us; speedup vs baseline: 2.0302x; 2.0302x over previous
//
#include <hip/hip_runtime.h>

// Guided blur (multichannel guided filter), B=8, C=Cp=3, H=W=512, k=5, eps=1e-4.
// Pass 1: blur 21 channels (I, p, I*I, I*p) per 32x32 tile, per-pixel 3x3 solve -> a[9], b[3] in d_ws.
// Pass 2: blur a,b (12 ch, all staged at once) per tile, combine with guidance -> out.
// d_ws usage: 8*12*512*512*4 = 100,663,296 bytes.

namespace {

constexpr int BN = 8;        // batch
constexpr int HH = 512;
constexpr int WW = 512;
constexpr float GEPS = 1e-4f;
constexpr int TILE = 32;
constexpr int HALO = 2;      // k//2
constexpr int LW = TILE + 2 * HALO;   // 36
constexpr int LST = LW + 1;           // 37: +1 pad, conflict-free rows

__device__ __forceinline__ int refl(int i, int n) {
    // jnp.pad(..., mode='reflect'): -1 -> 1, -2 -> 2, n -> n-2, n+1 -> n-3
    if (i < 0) i = -i;
    if (i >= n) i = 2 * n - 2 - i;
    return i;
}

__global__ __launch_bounds__(128, 4) void pass1_kernel(
        const float* __restrict__ g, const float* __restrict__ p,
        float* __restrict__ ab) {
    __shared__ float sb[6][LW][LST];
    const int x0 = blockIdx.x * TILE, y0 = blockIdx.y * TILE;
    const int bb = blockIdx.z;
    const int tx = threadIdx.x, ty = threadIdx.y;
    const int tid = ty * 32 + tx;
    const int csz = HH * WW;

    // Stage 6 base channel tiles (guidance 0..2, input 3..5) with reflect halo.
    for (int idx = tid; idx < 6 * LW * LW; idx += 128) {
        int c = idx / (LW * LW);
        int rem = idx - c * (LW * LW);
        int ly = rem / LW, lx = rem - ly * LW;
        int gy = refl(y0 + ly - HALO, HH);
        int gx = refl(x0 + lx - HALO, WW);
        const float* src = (c < 3) ? (g + (bb * 3 + c) * csz)
                                   : (p + (bb * 3 + (c - 3)) * csz);
        sb[c][ly][lx] = src[gy * WW + gx];
    }
    __syncthreads();

    const int col = tx;      // LDS col base; pixel col tx has window cols tx..tx+4
    const int r0 = ty * 8;   // this thread handles tile rows r0..r0+7

    float S[21];             // running 5x5 window sums
#pragma unroll
    for (int i = 0; i < 21; ++i) S[i] = 0.f;

    // signed accumulate of one row's horizontal 5-window of the 21 stat products
    auto rowacc = [&](int row, float sgn) {
#pragma unroll
        for (int dx = 0; dx < 5; ++dx) {
            float i0 = sb[0][row][col + dx];
            float i1 = sb[1][row][col + dx];
            float i2 = sb[2][row][col + dx];
            float q0 = sb[3][row][col + dx];
            float q1 = sb[4][row][col + dx];
            float q2 = sb[5][row][col + dx];
            S[0] += sgn * i0;  S[1] += sgn * i1;  S[2] += sgn * i2;
            S[3] += sgn * q0;  S[4] += sgn * q1;  S[5] += sgn * q2;
            float s0 = sgn * i0, s1 = sgn * i1, s2 = sgn * i2;
            S[6]  += s0 * i0; S[7]  += s0 * i1; S[8]  += s0 * i2;
            S[9]  += s1 * i1; S[10] += s1 * i2; S[11] += s2 * i2;
            S[12] += s0 * q0; S[13] += s0 * q1; S[14] += s0 * q2;
            S[15] += s1 * q0; S[16] += s1 * q1; S[17] += s1 * q2;
            S[18] += s2 * q0; S[19] += s2 * q1; S[20] += s2 * q2;
        }
    };

    // Prime with window rows r0..r0+3.
#pragma unroll 1
    for (int rr = 0; rr < 4; ++rr) rowacc(r0 + rr, 1.f);

    const int x = x0 + tx;
#pragma unroll 1
    for (int j = 0; j < 8; ++j) {
        rowacc(r0 + 4 + j, 1.f);   // add bottom row of this pixel's window

        // ---- finalize pixel (y0+r0+j, x) ----
        const float nrm = 0.04f;  // 1/25
        float mI0 = S[0] * nrm, mI1 = S[1] * nrm, mI2 = S[2] * nrm;
        float mP0 = S[3] * nrm, mP1 = S[4] * nrm, mP2 = S[5] * nrm;
        float v00 = S[6]  * nrm - mI0 * mI0 + GEPS;
        float v01 = S[7]  * nrm - mI0 * mI1;
        float v02 = S[8]  * nrm - mI0 * mI2;
        float v11 = S[9]  * nrm - mI1 * mI1 + GEPS;
        float v12 = S[10] * nrm - mI1 * mI2;
        float v22 = S[11] * nrm - mI2 * mI2 + GEPS;
        float c00 = S[12] * nrm - mI0 * mP0;
        float c01 = S[13] * nrm - mI0 * mP1;
        float c02 = S[14] * nrm - mI0 * mP2;
        float c10 = S[15] * nrm - mI1 * mP0;
        float c11 = S[16] * nrm - mI1 * mP1;
        float c12 = S[17] * nrm - mI1 * mP2;
        float c20 = S[18] * nrm - mI2 * mP0;
        float c21 = S[19] * nrm - mI2 * mP1;
        float c22 = S[20] * nrm - mI2 * mP2;
        // symmetric 3x3 inverse via adjugate
        float i00 = v11 * v22 - v12 * v12;
        float i01 = v02 * v12 - v01 * v22;
        float i02 = v01 * v12 - v02 * v11;
        float i11 = v00 * v22 - v02 * v02;
        float i12 = v01 * v02 - v00 * v12;
        float i22 = v00 * v11 - v01 * v01;
        float det = v00 * i00 + v01 * i01 + v02 * i02;
        float rd  = 1.0f / det;  // det > 0: A = PSD + eps*I
        float a00 = (i00 * c00 + i01 * c10 + i02 * c20) * rd;
        float a01 = (i00 * c01 + i01 * c11 + i02 * c21) * rd;
        float a02 = (i00 * c02 + i01 * c12 + i02 * c22) * rd;
        float a10 = (i01 * c00 + i11 * c10 + i12 * c20) * rd;
        float a11 = (i01 * c01 + i11 * c11 + i12 * c21) * rd;
        float a12 = (i01 * c02 + i11 * c12 + i12 * c22) * rd;
        float a20 = (i02 * c00 + i12 * c10 + i22 * c20) * rd;
        float a21 = (i02 * c01 + i12 * c11 + i22 * c21) * rd;
        float a22 = (i02 * c02 + i12 * c12 + i22 * c22) * rd;
        // b_p = mean_p_p - sum_c a[c][p] * mean_I_c
        float b0 = mP0 - (a00 * mI0 + a10 * mI1 + a20 * mI2);
        float b1 = mP1 - (a01 * mI0 + a11 * mI1 + a21 * mI2);
        float b2 = mP2 - (a02 * mI0 + a12 * mI1 + a22 * mI2);

        int y = y0 + r0 + j;
        int base = (bb * 12) * csz + y * WW + x;
        ab[base + 0  * csz] = a00;
        ab[base + 1  * csz] = a01;
        ab[base + 2  * csz] = a02;
        ab[base + 3  * csz] = a10;
        ab[base + 4  * csz] = a11;
        ab[base + 5  * csz] = a12;
        ab[base + 6  * csz] = a20;
        ab[base + 7  * csz] = a21;
        ab[base + 8  * csz] = a22;
        ab[base + 9  * csz] = b0;
        ab[base + 10 * csz] = b1;
        ab[base + 11 * csz] = b2;

        if (j < 7) rowacc(r0 + j, -1.f);  // remove top row of this pixel's window
    }
}

// 256 threads, all 12 channels staged once (63,936 B LDS -> 2 blocks/CU), one barrier.
__global__ __launch_bounds__(256) void pass2_kernel(
        const float* __restrict__ g, const float* __restrict__ ab,
        float* __restrict__ out) {
    __shared__ float sa[12][LW][LST];
    const int x0 = blockIdx.x * TILE, y0 = blockIdx.y * TILE;
    const int bb = blockIdx.z;
    const int tx = threadIdx.x, ty = threadIdx.y;   // (32, 8)
    const int tid = ty * 32 + tx;
    const int r0 = ty * 4;   // this thread outputs tile rows r0..r0+3
    const int x = x0 + tx;
    const int csz = HH * WW;

    // guidance for my 4 pixels x 3 channels (before barrier; independent of LDS)
    float gv[3][4];
#pragma unroll
    for (int c = 0; c < 3; ++c)
#pragma unroll
        for (int j = 0; j < 4; ++j)
            gv[c][j] = g[(bb * 3 + c) * csz + (y0 + r0 + j) * WW + x];

    // Stage all 12 ab channels with reflect halo.
    const float* abb = ab + (bb * 12) * csz;
    for (int idx = tid; idx < 12 * LW * LW; idx += 256) {
        int c = idx / (LW * LW);
        int rem = idx - c * (LW * LW);
        int ly = rem / LW, lx = rem - ly * LW;
        sa[c][ly][lx] = abb[c * csz + refl(y0 + ly - HALO, HH) * WW
                                    + refl(x0 + lx - HALO, WW)];
    }
    __syncthreads();

    float acc[3][4];
#pragma unroll
    for (int pp = 0; pp < 3; ++pp)
#pragma unroll
        for (int j = 0; j < 4; ++j) acc[pp][j] = 0.f;

#pragma unroll
    for (int ch = 0; ch < 12; ++ch) {
        // vertical rolling 5-window over 8 row-hsums (ring buffer of 5)
        float ring[5];
        float wsum = 0.f;
#pragma unroll
        for (int rr = 0; rr < 8; ++rr) {
            float hs = 0.f;
#pragma unroll
            for (int dx = 0; dx < 5; ++dx) hs += sa[ch][r0 + rr][tx + dx];
            if (rr >= 5) wsum -= ring[rr % 5];
            wsum += hs;
            ring[rr % 5] = hs;
            if (rr >= 4) {
                float mean = wsum * 0.04f;
                int j = rr - 4;
                if (ch < 9) acc[ch % 3][j] += mean * gv[ch / 3][j];
                else        acc[ch - 9][j] += mean;
            }
        }
    }

#pragma unroll
    for (int pp = 0; pp < 3; ++pp)
#pragma unroll
        for (int j = 0; j < 4; ++j)
            out[(bb * 3 + pp) * csz + (y0 + r0 + j) * WW + x] = acc[pp][j];
}

}  // namespace

extern "C" void kernel_launch(void* const* d_in, const int* in_sizes, int n_in,
                              void* d_out, int out_size, void* d_ws, size_t ws_size,
                              hipStream_t stream) {
    const float* g  = (const float*)d_in[0];   // guidance [8,3,512,512]
    const float* p  = (const float*)d_in[1];   // input    [8,3,512,512]
    float* out = (float*)d_out;                // [8,3,512,512]
    float* ab  = (float*)d_ws;                 // [8,12,512,512] a(9)+b(3)

    dim3 grid(WW / TILE, HH / TILE, BN);       // 16 x 16 x 8 = 2048 blocks
    dim3 block1(32, 4);                        // 128 threads
    dim3 block2(32, 8);                        // 256 threads

    hipLaunchKernelGGL(pass1_kernel, grid, block1, 0, stream, g, p, ab);
    hipLaunchKernelGGL(pass2_kernel, grid, block2, 0, stream, g, ab, out);
}

// Round 3
// 195.420 us; speedup vs baseline: 2.6305x; 1.2956x over previous
//
#include <hip/hip_runtime.h>

// Guided blur (multichannel guided filter), B=8, C=Cp=3, H=W=512, k=5, eps=1e-4.
// LDS-free, barrier-free structure:
//   - 64-lane wave owns columns x0-2 .. x0+61 (60 output cols + 2-col halo each side)
//   - vertical 5-row box sums rolled in registers down an 8-row strip (reads 12 rows)
//   - horizontal 5-tap via __shfl_down log-tree (3 bpermutes per window)
// Pass 1: 21 stat channels -> per-pixel 3x3 solve -> ab interleaved [b][y][x][12] in d_ws.
// Pass 2: vertical roll + shuffle blur of ab (12 ch) -> combine with guidance -> out.
// d_ws usage: 8*512*512*12*4 = 100,663,296 bytes.

namespace {

constexpr int BN = 8;
constexpr int HH = 512;
constexpr int WW = 512;
constexpr int CSZ = HH * WW;
constexpr float GEPS = 1e-4f;
constexpr int TW = 60;   // output cols per wave (64 lanes - 4 halo)
constexpr int SR = 8;    // output rows per wave strip
constexpr int WPB = 4;   // waves per block
constexpr int TH = SR * WPB;  // 32 output rows per block

__device__ __forceinline__ int refl(int i, int n) {
    // jnp.pad reflect: -1 -> 1, -2 -> 2, n -> n-2, n+1 -> n-3
    if (i < 0) i = -i;
    if (i >= n) i = 2 * n - 2 - i;
    return i;
}

// 5-tap forward sum across lanes: lane u gets v[u]+v[u+1]+v[u+2]+v[u+3]+v[u+4].
__device__ __forceinline__ float hsum5(float v) {
    float t = v + __shfl_down(v, 1);   // [u..u+1]
    float q = t + __shfl_down(t, 2);   // [u..u+3]
    return q + __shfl_down(v, 4);      // [u..u+4]
}

__global__ __launch_bounds__(256, 4) void pass1_kernel(
        const float* __restrict__ g, const float* __restrict__ p,
        float* __restrict__ ab) {
    const int lane = threadIdx.x & 63;
    const int wv   = threadIdx.x >> 6;
    const int x0   = blockIdx.x * TW;
    const int yb   = blockIdx.y * TH + wv * SR;
    const int bb   = blockIdx.z;

    const int xc = refl(x0 - 2 + lane, WW);      // owned column (reflected)
    const float* gB = g + (size_t)bb * 3 * CSZ;
    const float* pB = p + (size_t)bb * 3 * CSZ;

    float V[21];
#pragma unroll
    for (int i = 0; i < 21; ++i) V[i] = 0.f;
    float ring[5][6];

    const int x = x0 + lane;
    const bool wr = (lane < TW) && (x < WW);
    float* abBase = ab + ((size_t)bb * CSZ) * 12;

#pragma unroll
    for (int rr = 0; rr < SR + 4; ++rr) {
        const int y = refl(yb - 2 + rr, HH);
        const int off = y * WW + xc;
        float i0 = gB[off], i1 = gB[CSZ + off], i2 = gB[2 * CSZ + off];
        float q0 = pB[off], q1 = pB[CSZ + off], q2 = pB[2 * CSZ + off];

        V[0] += i0; V[1] += i1; V[2] += i2;
        V[3] += q0; V[4] += q1; V[5] += q2;
        V[6]  += i0 * i0; V[7]  += i0 * i1; V[8]  += i0 * i2;
        V[9]  += i1 * i1; V[10] += i1 * i2; V[11] += i2 * i2;
        V[12] += i0 * q0; V[13] += i0 * q1; V[14] += i0 * q2;
        V[15] += i1 * q0; V[16] += i1 * q1; V[17] += i1 * q2;
        V[18] += i2 * q0; V[19] += i2 * q1; V[20] += i2 * q2;

        if (rr >= 5) {   // drop row rr-5 (same ring slot as rr%5; read before overwrite)
            float o0 = ring[rr % 5][0], o1 = ring[rr % 5][1], o2 = ring[rr % 5][2];
            float r0 = ring[rr % 5][3], r1 = ring[rr % 5][4], r2 = ring[rr % 5][5];
            V[0] -= o0; V[1] -= o1; V[2] -= o2;
            V[3] -= r0; V[4] -= r1; V[5] -= r2;
            V[6]  -= o0 * o0; V[7]  -= o0 * o1; V[8]  -= o0 * o2;
            V[9]  -= o1 * o1; V[10] -= o1 * o2; V[11] -= o2 * o2;
            V[12] -= o0 * r0; V[13] -= o0 * r1; V[14] -= o0 * r2;
            V[15] -= o1 * r0; V[16] -= o1 * r1; V[17] -= o1 * r2;
            V[18] -= o2 * r0; V[19] -= o2 * r1; V[20] -= o2 * r2;
        }
        ring[rr % 5][0] = i0; ring[rr % 5][1] = i1; ring[rr % 5][2] = i2;
        ring[rr % 5][3] = q0; ring[rr % 5][4] = q1; ring[rr % 5][5] = q2;

        if (rr >= 4) {
            float S[21];
#pragma unroll
            for (int c = 0; c < 21; ++c) S[c] = hsum5(V[c]);

            const float nrm = 0.04f;  // 1/25
            float mI0 = S[0] * nrm, mI1 = S[1] * nrm, mI2 = S[2] * nrm;
            float mP0 = S[3] * nrm, mP1 = S[4] * nrm, mP2 = S[5] * nrm;
            float v00 = S[6]  * nrm - mI0 * mI0 + GEPS;
            float v01 = S[7]  * nrm - mI0 * mI1;
            float v02 = S[8]  * nrm - mI0 * mI2;
            float v11 = S[9]  * nrm - mI1 * mI1 + GEPS;
            float v12 = S[10] * nrm - mI1 * mI2;
            float v22 = S[11] * nrm - mI2 * mI2 + GEPS;
            float c00 = S[12] * nrm - mI0 * mP0;
            float c01 = S[13] * nrm - mI0 * mP1;
            float c02 = S[14] * nrm - mI0 * mP2;
            float c10 = S[15] * nrm - mI1 * mP0;
            float c11 = S[16] * nrm - mI1 * mP1;
            float c12 = S[17] * nrm - mI1 * mP2;
            float c20 = S[18] * nrm - mI2 * mP0;
            float c21 = S[19] * nrm - mI2 * mP1;
            float c22 = S[20] * nrm - mI2 * mP2;
            // symmetric 3x3 inverse via adjugate (A PD: PSD + eps*I)
            float i00 = v11 * v22 - v12 * v12;
            float i01 = v02 * v12 - v01 * v22;
            float i02 = v01 * v12 - v02 * v11;
            float i11 = v00 * v22 - v02 * v02;
            float i12 = v01 * v02 - v00 * v12;
            float i22 = v00 * v11 - v01 * v01;
            float det = v00 * i00 + v01 * i01 + v02 * i02;
            float rd  = 1.0f / det;
            float a00 = (i00 * c00 + i01 * c10 + i02 * c20) * rd;
            float a01 = (i00 * c01 + i01 * c11 + i02 * c21) * rd;
            float a02 = (i00 * c02 + i01 * c12 + i02 * c22) * rd;
            float a10 = (i01 * c00 + i11 * c10 + i12 * c20) * rd;
            float a11 = (i01 * c01 + i11 * c11 + i12 * c21) * rd;
            float a12 = (i01 * c02 + i11 * c12 + i12 * c22) * rd;
            float a20 = (i02 * c00 + i12 * c10 + i22 * c20) * rd;
            float a21 = (i02 * c01 + i12 * c11 + i22 * c21) * rd;
            float a22 = (i02 * c02 + i12 * c12 + i22 * c22) * rd;
            float b0 = mP0 - (a00 * mI0 + a10 * mI1 + a20 * mI2);
            float b1 = mP1 - (a01 * mI0 + a11 * mI1 + a21 * mI2);
            float b2 = mP2 - (a02 * mI0 + a12 * mI1 + a22 * mI2);

            if (wr) {
                const int yo = yb + rr - 4;
                float4* dst = (float4*)(abBase + (size_t)(yo * WW + x) * 12);
                dst[0] = make_float4(a00, a01, a02, a10);
                dst[1] = make_float4(a11, a12, a20, a21);
                dst[2] = make_float4(a22, b0, b1, b2);
            }
        }
    }
}

__global__ __launch_bounds__(256, 4) void pass2_kernel(
        const float* __restrict__ g, const float* __restrict__ ab,
        float* __restrict__ out) {
    const int lane = threadIdx.x & 63;
    const int wv   = threadIdx.x >> 6;
    const int x0   = blockIdx.x * TW;
    const int yb   = blockIdx.y * TH + wv * SR;
    const int bb   = blockIdx.z;

    const int xc = refl(x0 - 2 + lane, WW);
    const float4* abB = (const float4*)ab + (size_t)bb * CSZ * 3;
    const float* gB = g + (size_t)bb * 3 * CSZ;
    float* oB = out + (size_t)bb * 3 * CSZ;

    float V[12];
#pragma unroll
    for (int i = 0; i < 12; ++i) V[i] = 0.f;
    float ring[5][12];

    const int x = x0 + lane;
    const bool wr = (lane < TW) && (x < WW);

#pragma unroll
    for (int rr = 0; rr < SR + 4; ++rr) {
        const int y = refl(yb - 2 + rr, HH);
        const float4* src = abB + (size_t)(y * WW + xc) * 3;
        float4 L0 = src[0], L1 = src[1], L2 = src[2];
        float cur[12] = {L0.x, L0.y, L0.z, L0.w,
                         L1.x, L1.y, L1.z, L1.w,
                         L2.x, L2.y, L2.z, L2.w};
#pragma unroll
        for (int c = 0; c < 12; ++c) {
            V[c] += cur[c];
            if (rr >= 5) V[c] -= ring[rr % 5][c];   // read before overwrite
            ring[rr % 5][c] = cur[c];
        }

        if (rr >= 4) {
            float M[12];
#pragma unroll
            for (int c = 0; c < 12; ++c) M[c] = hsum5(V[c]) * 0.04f;

            if (wr) {
                const int yo = yb + rr - 4;
                const int o = yo * WW + x;
                float g0 = gB[o], g1 = gB[CSZ + o], g2 = gB[2 * CSZ + o];
                // a[c][p] = M[3c+p]; out_p = sum_c g_c * mean_a[c][p] + mean_b_p
                oB[o]           = g0 * M[0] + g1 * M[3] + g2 * M[6] + M[9];
                oB[CSZ + o]     = g0 * M[1] + g1 * M[4] + g2 * M[7] + M[10];
                oB[2 * CSZ + o] = g0 * M[2] + g1 * M[5] + g2 * M[8] + M[11];
            }
        }
    }
}

}  // namespace

extern "C" void kernel_launch(void* const* d_in, const int* in_sizes, int n_in,
                              void* d_out, int out_size, void* d_ws, size_t ws_size,
                              hipStream_t stream) {
    const float* g  = (const float*)d_in[0];   // guidance [8,3,512,512]
    const float* p  = (const float*)d_in[1];   // input    [8,3,512,512]
    float* out = (float*)d_out;                // [8,3,512,512]
    float* ab  = (float*)d_ws;                 // [8,512,512,12] interleaved a(9)+b(3)

    dim3 grid((WW + TW - 1) / TW, HH / TH, BN);   // (9, 16, 8) = 1152 blocks
    dim3 block(WPB * 64);                          // 256 threads = 4 waves

    hipLaunchKernelGGL(pass1_kernel, grid, block, 0, stream, g, p, ab);
    hipLaunchKernelGGL(pass2_kernel, grid, block, 0, stream, g, ab, out);
}

// Round 4
// 162.434 us; speedup vs baseline: 3.1646x; 1.2031x over previous
//
#include <hip/hip_runtime.h>

// Guided blur (multichannel guided filter), B=8, C=Cp=3, H=W=512, k=5, eps=1e-4.
// LDS-free, barrier-free, shuffle-free (DPP-only) structure:
//   - wave = 4 x 16-lane segments; each segment owns 12 output cols + 2-col halo/side
//   - horizontal 5-tap sums via v_add + DPP row_shl:{1,2,4} (VALU pipe, no LDS pipe)
//   - vertical 5-row box sums rolled in registers down a 16-row strip (reads 20 rows)
//   - row loads software-pipelined 3 deep (P[3] prefetch buffers, full unroll)
// Pass 1: 21 stat channels -> per-pixel 3x3 solve -> ab interleaved [b][y][x][12] in d_ws.
// Pass 2: vertical roll + DPP blur of ab (12 ch) -> combine with guidance -> out.
// d_ws usage: 8*512*512*12*4 = 100,663,296 bytes.

namespace {

constexpr int BN = 8;
constexpr int HH = 512;
constexpr int WW = 512;
constexpr int CSZ = HH * WW;
constexpr float GEPS = 1e-4f;
constexpr int SEGW = 12;            // output cols per 16-lane segment
constexpr int BW   = 4 * SEGW;      // 48 output cols per wave
constexpr int SR   = 16;            // output rows per wave strip (reads SR+4)
constexpr int WPB  = 2;             // waves per block
constexpr int TH   = SR * WPB;      // 32 output rows per block

__device__ __forceinline__ int refl(int i, int n) {
    // jnp.pad reflect: -1 -> 1, -2 -> 2, n -> n-2, n+1 -> n-3
    if (i < 0) i = -i;
    if (i >= n) i = 2 * n - 2 - i;
    return i;
}

// DPP row_shl:N within 16-lane row: lane u receives lane u+N (0 beyond row end).
template <int N>
__device__ __forceinline__ float shlN(float v) {
    return __builtin_bit_cast(float,
        __builtin_amdgcn_update_dpp(0, __builtin_bit_cast(int, v),
                                    0x100 + N, 0xF, 0xF, true));
}
// lane u (row-local) gets v[u]+v[u+1]+v[u+2]+v[u+3]+v[u+4]; valid for u <= 11.
__device__ __forceinline__ float hsum5(float v) {
    float t = v + shlN<1>(v);
    float q = t + shlN<2>(t);
    return q + shlN<4>(v);
}

__global__ __launch_bounds__(128, 3) void pass1_kernel(
        const float* __restrict__ g, const float* __restrict__ p,
        float* __restrict__ ab) {
    const int lane = threadIdx.x & 63;
    const int wv   = threadIdx.x >> 6;
    const int l    = lane & 15;
    const int seg  = lane >> 4;
    const int x0   = blockIdx.x * BW;
    const int yb   = blockIdx.y * TH + wv * SR;
    const int bb   = blockIdx.z;

    const int xr = refl(x0 + seg * SEGW - 2 + l, WW);  // raw read col
    const int x  = x0 + seg * SEGW + l;                // output col
    const bool wr = (l < SEGW) && (x < WW);

    const float* gB = g + (size_t)bb * 3 * CSZ;
    const float* pB = p + (size_t)bb * 3 * CSZ;
    float* abB = ab + (size_t)bb * CSZ * 12;

    float V[21];
#pragma unroll
    for (int i = 0; i < 21; ++i) V[i] = 0.f;
    float ring[5][6];
    float P[3][6];     // 3-deep row prefetch

    auto loadrow = [&](int rr, float dst[6]) {
        const int y = refl(yb - 2 + rr, HH);
        const int off = y * WW + xr;
        dst[0] = gB[off]; dst[1] = gB[CSZ + off]; dst[2] = gB[2 * CSZ + off];
        dst[3] = pB[off]; dst[4] = pB[CSZ + off]; dst[5] = pB[2 * CSZ + off];
    };
    auto accum = [&](const float c[6], float sgn) {
        float i0 = c[0], i1 = c[1], i2 = c[2], q0 = c[3], q1 = c[4], q2 = c[5];
        float s0 = sgn * i0, s1 = sgn * i1, s2 = sgn * i2;
        float t0 = sgn * q0, t1 = sgn * q1, t2 = sgn * q2;
        V[0] += s0; V[1] += s1; V[2] += s2;
        V[3] += t0; V[4] += t1; V[5] += t2;
        V[6]  += s0 * i0; V[7]  += s0 * i1; V[8]  += s0 * i2;
        V[9]  += s1 * i1; V[10] += s1 * i2; V[11] += s2 * i2;
        V[12] += s0 * q0; V[13] += s0 * q1; V[14] += s0 * q2;
        V[15] += s1 * q0; V[16] += s1 * q1; V[17] += s1 * q2;
        V[18] += s2 * q0; V[19] += s2 * q1; V[20] += s2 * q2;
    };

    loadrow(0, P[0]); loadrow(1, P[1]); loadrow(2, P[2]);

#pragma unroll
    for (int rr = 0; rr < SR + 4; ++rr) {
        float cur[6];
#pragma unroll
        for (int c = 0; c < 6; ++c) cur[c] = P[rr % 3][c];
        if (rr + 3 < SR + 4) loadrow(rr + 3, P[rr % 3]);

        accum(cur, 1.f);
        if (rr >= 5) accum(ring[rr % 5], -1.f);   // drop row rr-5
#pragma unroll
        for (int c = 0; c < 6; ++c) ring[rr % 5][c] = cur[c];

        if (rr >= 4) {
            float S[21];
#pragma unroll
            for (int c = 0; c < 21; ++c) S[c] = hsum5(V[c]);

            const float nrm = 0.04f;  // 1/25
            float mI0 = S[0] * nrm, mI1 = S[1] * nrm, mI2 = S[2] * nrm;
            float mP0 = S[3] * nrm, mP1 = S[4] * nrm, mP2 = S[5] * nrm;
            float v00 = S[6]  * nrm - mI0 * mI0 + GEPS;
            float v01 = S[7]  * nrm - mI0 * mI1;
            float v02 = S[8]  * nrm - mI0 * mI2;
            float v11 = S[9]  * nrm - mI1 * mI1 + GEPS;
            float v12 = S[10] * nrm - mI1 * mI2;
            float v22 = S[11] * nrm - mI2 * mI2 + GEPS;
            float c00 = S[12] * nrm - mI0 * mP0;
            float c01 = S[13] * nrm - mI0 * mP1;
            float c02 = S[14] * nrm - mI0 * mP2;
            float c10 = S[15] * nrm - mI1 * mP0;
            float c11 = S[16] * nrm - mI1 * mP1;
            float c12 = S[17] * nrm - mI1 * mP2;
            float c20 = S[18] * nrm - mI2 * mP0;
            float c21 = S[19] * nrm - mI2 * mP1;
            float c22 = S[20] * nrm - mI2 * mP2;
            // symmetric 3x3 inverse via adjugate (A PD: PSD + eps*I)
            float i00 = v11 * v22 - v12 * v12;
            float i01 = v02 * v12 - v01 * v22;
            float i02 = v01 * v12 - v02 * v11;
            float i11 = v00 * v22 - v02 * v02;
            float i12 = v01 * v02 - v00 * v12;
            float i22 = v00 * v11 - v01 * v01;
            float det = v00 * i00 + v01 * i01 + v02 * i02;
            float rd  = 1.0f / det;
            float a00 = (i00 * c00 + i01 * c10 + i02 * c20) * rd;
            float a01 = (i00 * c01 + i01 * c11 + i02 * c21) * rd;
            float a02 = (i00 * c02 + i01 * c12 + i02 * c22) * rd;
            float a10 = (i01 * c00 + i11 * c10 + i12 * c20) * rd;
            float a11 = (i01 * c01 + i11 * c11 + i12 * c21) * rd;
            float a12 = (i01 * c02 + i11 * c12 + i12 * c22) * rd;
            float a20 = (i02 * c00 + i12 * c10 + i22 * c20) * rd;
            float a21 = (i02 * c01 + i12 * c11 + i22 * c21) * rd;
            float a22 = (i02 * c02 + i12 * c12 + i22 * c22) * rd;
            float b0 = mP0 - (a00 * mI0 + a10 * mI1 + a20 * mI2);
            float b1 = mP1 - (a01 * mI0 + a11 * mI1 + a21 * mI2);
            float b2 = mP2 - (a02 * mI0 + a12 * mI1 + a22 * mI2);

            if (wr) {
                const int yo = yb + rr - 4;
                float4* dst = (float4*)(abB + (size_t)(yo * WW + x) * 12);
                dst[0] = make_float4(a00, a01, a02, a10);
                dst[1] = make_float4(a11, a12, a20, a21);
                dst[2] = make_float4(a22, b0, b1, b2);
            }
        }
    }
}

__global__ __launch_bounds__(128, 3) void pass2_kernel(
        const float* __restrict__ g, const float* __restrict__ ab,
        float* __restrict__ out) {
    const int lane = threadIdx.x & 63;
    const int wv   = threadIdx.x >> 6;
    const int l    = lane & 15;
    const int seg  = lane >> 4;
    const int x0   = blockIdx.x * BW;
    const int yb   = blockIdx.y * TH + wv * SR;
    const int bb   = blockIdx.z;

    const int xr = refl(x0 + seg * SEGW - 2 + l, WW);  // ab read col
    const int x  = x0 + seg * SEGW + l;                // output col
    const int xs = (x < WW) ? x : (WW - 1);            // safe col for g loads
    const bool wr = (l < SEGW) && (x < WW);

    const float4* abB = (const float4*)ab + (size_t)bb * CSZ * 3;
    const float* gB = g + (size_t)bb * 3 * CSZ;
    float* oB = out + (size_t)bb * 3 * CSZ;

    float V[12];
#pragma unroll
    for (int i = 0; i < 12; ++i) V[i] = 0.f;
    float ring[5][12];
    float P[3][12];

    auto loadrow = [&](int rr, float dst[12]) {
        const int y = refl(yb - 2 + rr, HH);
        const float4* src = abB + (size_t)(y * WW + xr) * 3;
        float4 L0 = src[0], L1 = src[1], L2 = src[2];
        dst[0] = L0.x; dst[1] = L0.y; dst[2]  = L0.z; dst[3]  = L0.w;
        dst[4] = L1.x; dst[5] = L1.y; dst[6]  = L1.z; dst[7]  = L1.w;
        dst[8] = L2.x; dst[9] = L2.y; dst[10] = L2.z; dst[11] = L2.w;
    };

    loadrow(0, P[0]); loadrow(1, P[1]); loadrow(2, P[2]);

#pragma unroll
    for (int rr = 0; rr < SR + 4; ++rr) {
        float cur[12];
#pragma unroll
        for (int c = 0; c < 12; ++c) cur[c] = P[rr % 3][c];
        if (rr + 3 < SR + 4) loadrow(rr + 3, P[rr % 3]);

#pragma unroll
        for (int c = 0; c < 12; ++c) {
            V[c] += cur[c];
            if (rr >= 5) V[c] -= ring[rr % 5][c];
            ring[rr % 5][c] = cur[c];
        }

        if (rr >= 4) {
            float M[12];
#pragma unroll
            for (int c = 0; c < 12; ++c) M[c] = hsum5(V[c]) * 0.04f;

            const int yo = yb + rr - 4;
            const int o = yo * WW + xs;
            float g0 = gB[o], g1 = gB[CSZ + o], g2 = gB[2 * CSZ + o];
            // a[c][p] = M[3c+p]; out_p = sum_c g_c * mean_a[c][p] + mean_b_p
            float o0 = g0 * M[0] + g1 * M[3] + g2 * M[6] + M[9];
            float o1 = g0 * M[1] + g1 * M[4] + g2 * M[7] + M[10];
            float o2 = g0 * M[2] + g1 * M[5] + g2 * M[8] + M[11];
            if (wr) {
                oB[o]           = o0;
                oB[CSZ + o]     = o1;
                oB[2 * CSZ + o] = o2;
            }
        }
    }
}

}  // namespace

extern "C" void kernel_launch(void* const* d_in, const int* in_sizes, int n_in,
                              void* d_out, int out_size, void* d_ws, size_t ws_size,
                              hipStream_t stream) {
    const float* g  = (const float*)d_in[0];   // guidance [8,3,512,512]
    const float* p  = (const float*)d_in[1];   // input    [8,3,512,512]
    float* out = (float*)d_out;                // [8,3,512,512]
    float* ab  = (float*)d_ws;                 // [8,512,512,12] interleaved a(9)+b(3)

    dim3 grid((WW + BW - 1) / BW, HH / TH, BN);   // (11, 16, 8) = 1408 blocks
    dim3 block(WPB * 64);                          // 128 threads = 2 waves

    hipLaunchKernelGGL(pass1_kernel, grid, block, 0, stream, g, p, ab);
    hipLaunchKernelGGL(pass2_kernel, grid, block, 0, stream, g, ab, out);
}